// Round 1
// baseline (67.236 us; speedup 1.0000x reference)
//
#include <hip/hip_runtime.h>

// out[0, n*96+j, l, m] = sum_{g<24} W[n*96+j][g] * x[n*24+g, m, l]
// W[o][g] = sum_{i<9} w0[o%96, i] * w1[(o/96)*24+g, i]
//
// x:  [48][56][56]  (c, m, l)  -- note spatial transpose vs output
// out:[192][56][56] (o, l, m)

#define S    56        // spatial dim
#define SP   3136      // 56*56
#define G    24        // channels summed per group
#define LB   4         // l-values per block
#define JB   12        // output channels per block
#define NW   (192*G)   // W element count = 4608

__global__ __launch_bounds__(256)
void w_precompute(const float* __restrict__ w0, const float* __restrict__ w1,
                  float* __restrict__ W) {
    int idx = threadIdx.x + blockIdx.x * 256;
    if (idx < NW) {
        int o = idx / G, g = idx % G;
        int n = o / 96, j = o % 96;
        int c = n * G + g;
        float s = 0.f;
        #pragma unroll
        for (int i = 0; i < 9; ++i)
            s += w0[j * 9 + i] * w1[c * 9 + i];
        W[idx] = s;
    }
}

// Main kernel: W read from global scratch -> wave-uniform scalar loads.
// grid = (14, 8, 2): l-chunk, j-chunk, n. block = 256.
__global__ __launch_bounds__(256)
void conv_mix(const float* __restrict__ x, const float* __restrict__ W,
              float* __restrict__ out) {
    __shared__ float xs[G * LB * S];   // xs[g][ll][m] = x[n*24+g][m][l0+ll], 21 KB
    const int l0  = blockIdx.x * LB;
    const int j0  = blockIdx.y * JB;
    const int n   = blockIdx.z;
    const int tid = threadIdx.x;

    const float* xn = x + n * G * SP;
    // ---- stage x tile (transpose m<->l lives in the LDS addressing) ----
    // idx decomposition: ll fastest -> lanes read 4 contiguous floats (16B
    // segments) of the l-contiguous input; LDS store is stride-56 = 2-way
    // bank aliasing (free).
    #pragma unroll
    for (int it = 0; it < (G * LB * S) / 256; ++it) {
        int idx = it * 256 + tid;
        int ll = idx & (LB - 1);
        int m  = (idx >> 2) % S;
        int g  = idx / (LB * S);
        xs[(g * LB + ll) * S + m] = xn[g * SP + m * S + l0 + ll];
    }
    __syncthreads();

    // ---- compute: one thread per (ll, m) position, 12 output channels ----
    if (tid < LB * S) {
        const int ll = tid / S;
        const int m  = tid % S;      // lanes consecutive -> m consecutive
        float xv[G];
        #pragma unroll
        for (int g = 0; g < G; ++g)
            xv[g] = xs[(g * LB + ll) * S + m];   // conflict-free

        const int l = l0 + ll;
        float* orow = out + (size_t)(n * 96 + j0) * SP + l * S + m;
        const float* wrow = W + (n * 96 + j0) * G;   // wave-uniform -> s_load
        #pragma unroll
        for (int j = 0; j < JB; ++j) {
            float acc = 0.f;
            #pragma unroll
            for (int g = 0; g < G; ++g)
                acc += wrow[j * G + g] * xv[g];
            orow[j * SP] = acc;      // contiguous 224B row per 56 lanes
        }
    }
}

// Fallback (no workspace): per-block W chunk computed into LDS.
__global__ __launch_bounds__(256)
void conv_mix_fused(const float* __restrict__ x, const float* __restrict__ w0,
                    const float* __restrict__ w1, float* __restrict__ out) {
    __shared__ float xs[G * LB * S];
    __shared__ float Wl[JB * G];
    const int l0  = blockIdx.x * LB;
    const int j0  = blockIdx.y * JB;
    const int n   = blockIdx.z;
    const int tid = threadIdx.x;

    for (int idx = tid; idx < JB * G; idx += 256) {
        int j = idx / G, g = idx % G;
        float s = 0.f;
        #pragma unroll
        for (int i = 0; i < 9; ++i)
            s += w0[(j0 + j) * 9 + i] * w1[(n * G + g) * 9 + i];
        Wl[idx] = s;
    }

    const float* xn = x + n * G * SP;
    #pragma unroll
    for (int it = 0; it < (G * LB * S) / 256; ++it) {
        int idx = it * 256 + tid;
        int ll = idx & (LB - 1);
        int m  = (idx >> 2) % S;
        int g  = idx / (LB * S);
        xs[(g * LB + ll) * S + m] = xn[g * SP + m * S + l0 + ll];
    }
    __syncthreads();

    if (tid < LB * S) {
        const int ll = tid / S;
        const int m  = tid % S;
        float xv[G];
        #pragma unroll
        for (int g = 0; g < G; ++g)
            xv[g] = xs[(g * LB + ll) * S + m];

        const int l = l0 + ll;
        float* orow = out + (size_t)(n * 96 + j0) * SP + l * S + m;
        #pragma unroll
        for (int j = 0; j < JB; ++j) {
            float acc = 0.f;
            #pragma unroll
            for (int g = 0; g < G; ++g)
                acc += Wl[j * G + g] * xv[g];   // LDS broadcast
            orow[j * SP] = acc;
        }
    }
}

extern "C" void kernel_launch(void* const* d_in, const int* in_sizes, int n_in,
                              void* d_out, int out_size, void* d_ws, size_t ws_size,
                              hipStream_t stream) {
    const float* x  = (const float*)d_in[0];
    const float* w0 = (const float*)d_in[1];
    const float* w1 = (const float*)d_in[2];
    float* out = (float*)d_out;

    dim3 grid(S / LB, 96 / JB, 2);   // (14, 8, 2) = 224 blocks

    if (ws_size >= (size_t)NW * sizeof(float)) {
        float* W = (float*)d_ws;
        w_precompute<<<(NW + 255) / 256, 256, 0, stream>>>(w0, w1, W);
        conv_mix<<<grid, 256, 0, stream>>>(x, W, out);
    } else {
        conv_mix_fused<<<grid, 256, 0, stream>>>(x, w0, w1, out);
    }
}

// Round 2
// 60.925 us; speedup vs baseline: 1.1036x; 1.1036x over previous
//
#include <hip/hip_runtime.h>

// out[0, n*96+j, l, m] = sum_{g<24} W[n*96+j][g] * x[n*24+g, m, l]
// W[o][g] = sum_{i<9} w0[o%96, i] * w1[(o/96)*24+g, i]
//
// x:  [48][56][56]  (c, m, l)  -- note spatial transpose vs output
// out:[192][56][56] (o, l, m)
//
// Single fused kernel: W chunk (12x24 per block) recomputed into LDS
// (288 elems x 9 MACs, trivial), x tile transposed through LDS, each
// compute thread holds xv[24] in VGPRs and emits 12 output channels.

#define S    56        // spatial dim
#define SP   3136      // 56*56
#define G    24        // channels summed per group
#define LB   4         // l-values per block
#define JB   12        // output channels per block

__global__ __launch_bounds__(256)
void conv_mix_fused(const float* __restrict__ x, const float* __restrict__ w0,
                    const float* __restrict__ w1, float* __restrict__ out) {
    __shared__ float xs[G * LB * S];   // 21 KB: xs[g][ll][m]
    __shared__ float Wl[JB * G];       // 1.1 KB
    const int l0  = blockIdx.x * LB;
    const int j0  = blockIdx.y * JB;
    const int n   = blockIdx.z;
    const int tid = threadIdx.x;

    // ---- per-block weight fold: Wl[j][g] = sum_i w0[j0+j,i]*w1[n*24+g,i] ----
    for (int idx = tid; idx < JB * G; idx += 256) {
        int j = idx / G, g = idx % G;
        float s = 0.f;
        #pragma unroll
        for (int i = 0; i < 9; ++i)
            s += w0[(j0 + j) * 9 + i] * w1[(n * G + g) * 9 + i];
        Wl[idx] = s;
    }

    // ---- stage x tile (m<->l transpose lives in LDS addressing) ----
    // ll fastest -> each lane-group reads 16B contiguous segments of the
    // l-contiguous input; LDS store stride-56 = 2-way bank alias (free).
    const float* xn = x + n * G * SP;
    #pragma unroll
    for (int it = 0; it < (G * LB * S) / 256; ++it) {
        int idx = it * 256 + tid;
        int ll = idx & (LB - 1);
        int m  = (idx >> 2) % S;
        int g  = idx / (LB * S);
        xs[(g * LB + ll) * S + m] = xn[g * SP + m * S + l0 + ll];
    }
    __syncthreads();

    // ---- compute: one thread per (ll, m), 12 output channels ----
    if (tid < LB * S) {
        const int ll = tid / S;
        const int m  = tid % S;      // lanes consecutive -> m consecutive
        float xv[G];
        #pragma unroll
        for (int g = 0; g < G; ++g)
            xv[g] = xs[(g * LB + ll) * S + m];   // conflict-free

        const int l = l0 + ll;
        float* orow = out + (size_t)(n * 96 + j0) * SP + l * S + m;
        #pragma unroll
        for (int j = 0; j < JB; ++j) {
            float acc = 0.f;
            #pragma unroll
            for (int g = 0; g < G; ++g)
                acc += Wl[j * G + g] * xv[g];    // LDS broadcast, ds_read_b128-able
            orow[j * SP] = acc;                  // contiguous 224B row
        }
    }
}

extern "C" void kernel_launch(void* const* d_in, const int* in_sizes, int n_in,
                              void* d_out, int out_size, void* d_ws, size_t ws_size,
                              hipStream_t stream) {
    const float* x  = (const float*)d_in[0];
    const float* w0 = (const float*)d_in[1];
    const float* w1 = (const float*)d_in[2];
    float* out = (float*)d_out;
    (void)d_ws; (void)ws_size;

    dim3 grid(S / LB, 96 / JB, 2);   // (14, 8, 2) = 224 blocks
    conv_mix_fused<<<grid, 256, 0, stream>>>(x, w0, w1, out);
}